// Round 3
// baseline (483.264 us; speedup 1.0000x reference)
//
#include <hip/hip_runtime.h>
#include <hip/hip_bf16.h>

#define NAGENTS 32768
#define SLAB    65536            // NAGENTS*2 floats per time-step
#define SPLIT   1310720          // 20*SLAB
#define SPLIT4  327680           // SPLIT/4
#define PRED    30
#define IN_F    40
#define LN_EPS  1e-5f
#define APB     64               // agents per block
#define NBLK    (NAGENTS/APB)    // 512 = 2 blocks/CU, all co-resident (required!)
#define BTH     512              // 8 waves/block
#define XSTRIDE 104              // shorts per agent row in Xs (96 used + 8 pad)

// Xs k-layout (gates A operand): k 0..63 = h, k 64..79 = x, k 80..95 = 0.
// h-part GEMM (k slices 0,1) depends only on last step's h -> runs at step
// start, off the fresh-data critical path. x-part is 1 slice (ks=2).

// out-chunk granularity for flags: one producer block-step = 128 floats.
// chunk i: t = i>>9, p = i&511.

typedef short bf16x8 __attribute__((ext_vector_type(8)));
typedef float f32x4  __attribute__((ext_vector_type(4)));

#define C_SGW  0      // 16  : sum_f ln1g[f]*embW[e,f]
#define C_BW   16     // 16  : sum_f ln1b[f]*embW[e,f] + emb_b[e]
#define C_G2   32     // 128 : g2WT[k*2+d] = ln2g[k]*h2pW[d,k]
#define C_SG2  160    // 2
#define C_B2   162    // 2
#define C_BIAS 164    // 256 : b_ih + b_hh
#define C_TOT  420

__device__ __forceinline__ float frcp(float x){ return __builtin_amdgcn_rcpf(x); }
__device__ __forceinline__ float fsigmoid(float x){ return frcp(1.f + __expf(-x)); }
__device__ __forceinline__ float ftanh(float x){
    float t = __expf(-2.f*fabsf(x));
    float r = (1.f - t) * frcp(1.f + t);
    return copysignf(r, x);
}
__device__ __forceinline__ float lrelu(float x){ return x > 0.f ? x : 0.01f*x; }
__device__ __forceinline__ short f2bf(float x){
    unsigned u = __float_as_uint(x);
    return (short)((u + 0x7FFFu + ((u>>16)&1u)) >> 16);   // RNE
}
__device__ __forceinline__ float bf2f(short s){
    return __uint_as_float(((unsigned)(unsigned short)s) << 16);
}

__global__ __launch_bounds__(BTH, 4)
void persist_kernel(const float* __restrict__ traj,
                    float* __restrict__ out,
                    const float* __restrict__ dec_h,
                    const float* __restrict__ W_ih, const float* __restrict__ W_hh,
                    const float* __restrict__ b_ih, const float* __restrict__ b_hh,
                    const float* __restrict__ emb_W, const float* __restrict__ emb_b,
                    const float* __restrict__ h2p_W, const float* __restrict__ h2p_b,
                    const float* __restrict__ ln1_g, const float* __restrict__ ln1_b,
                    const float* __restrict__ ln2_g, const float* __restrict__ ln2_b,
                    int* __restrict__ flags)   // ws: flags[b] = # steps block b completed
{
    __shared__ short Xs[APB*XSTRIDE];   // gates A operand, layout above
    __shared__ float St[APB*2];         // LN1 stats: m, inv per agent row
    __shared__ float cst[C_TOT];

    const int tid  = threadIdx.x;
    const int bid  = blockIdx.x;
    const int a0   = bid * APB;
    const int l    = tid & 63;
    const int wv   = tid >> 6;            // 0..7
    const int gang = wv >> 2;             // 0..1 : 32 agents each (gates GEMM)
    const int wvin = wv & 3;
    const int cl   = l & 15;
    const int kb   = l >> 4;
    const int nh   = wvin*16 + cl;        // gate-elem column this lane owns

    // ---- one-time folded-constant precompute (per block) ----
    if (tid < 16) {
        int e = tid;
        float s = 0.f, b = 0.f;
        for (int f = 0; f < IN_F; ++f) {
            float wf = emb_W[e*40 + f];
            s += ln1_g[f] * wf;
            b += ln1_b[f] * wf;
        }
        cst[C_SGW + e] = s;
        cst[C_BW + e]  = b + emb_b[e];
    }
    if (tid < 128) {
        int k = tid >> 1, d = tid & 1;
        cst[C_G2 + tid] = ln2_g[k] * h2p_W[d*64 + k];
    }
    if (tid < 2) {
        int d = tid;
        float s = 0.f, b = 0.f;
        for (int k = 0; k < 64; ++k) {
            float wf = h2p_W[d*64 + k];
            s += ln2_g[k] * wf;
            b += ln2_b[k] * wf;
        }
        cst[C_SG2 + d] = s;
        cst[C_B2 + d]  = b + h2p_b[d];
    }
    if (tid >= 256) cst[C_BIAS + tid - 256] = b_ih[tid-256] + b_hh[tid-256];

    // ---- gates-B fragments: k 0..63 W_hh, 64..79 W_ih, 80..95 zero ----
    bf16x8 bw[4][3];
#pragma unroll
    for (int g = 0; g < 4; ++g)
#pragma unroll
        for (int ks = 0; ks < 3; ++ks) {
            int n = g*64 + nh;
            bf16x8 v;
#pragma unroll
            for (int j = 0; j < 8; ++j) {
                int k = ks*32 + kb*8 + j;
                float f = 0.f;
                if (k < 64)      f = W_hh[n*64 + k];
                else if (k < 80) f = W_ih[n*16 + (k-64)];
                v[j] = f2bf(f);
            }
            bw[g][ks] = v;
        }

    // ---- embedding-B fragments: B[k=f][n=e] = ln1g[f]*embW[e,f], k>=40 -> 0 ----
    bf16x8 ew[2];
#pragma unroll
    for (int ks = 0; ks < 2; ++ks) {
        bf16x8 v;
#pragma unroll
        for (int j = 0; j < 8; ++j) {
            int k = ks*32 + kb*8 + j;
            float f = (k < IN_F) ? ln1_g[k] * emb_W[cl*40 + k] : 0.f;
            v[j] = f2bf(f);
        }
        ew[ks] = v;
    }

    // ---- init Xs.h from dec_h (k 0..63); zero k-pad [80,96) once ----
    for (int i = tid; i < APB*16; i += BTH) {
        int a = i >> 4, q = i & 15;
        float4 hv = ((const float4*)dec_h)[(a0 + a)*16 + q];
        __hip_bfloat162 p0 = __float22bfloat162_rn(float2{hv.x, hv.y});
        __hip_bfloat162 p1 = __float22bfloat162_rn(float2{hv.z, hv.w});
        uint2 pv{ *reinterpret_cast<unsigned*>(&p0), *reinterpret_cast<unsigned*>(&p1) };
        *(uint2*)&Xs[a*XSTRIDE + q*4] = pv;
    }
    if (tid < APB*2) {      // Xs k-pad [80,96)
        int a = tid >> 1, hf = tid & 1;
        *(bf16x8*)&Xs[a*XSTRIDE + 80 + hf*8] = bf16x8{0,0,0,0,0,0,0,0};
    }

    // ---- c state fp32 in registers for all 30 steps ----
    float cs[2][4];
#pragma unroll
    for (int mt = 0; mt < 2; ++mt)
#pragma unroll
        for (int r = 0; r < 4; ++r) cs[mt][r] = 0.f;

    __syncthreads();

    for (int s = 0; s < PRED; ++s) {
        // ---- acc = bias; h-part GEMM off the critical path ----
        f32x4 acc[2][4];
#pragma unroll
        for (int g = 0; g < 4; ++g) {
            float bb = cst[C_BIAS + g*64 + nh];
            acc[0][g] = f32x4{bb, bb, bb, bb};
            acc[1][g] = f32x4{bb, bb, bb, bb};
        }

        if (wv < 4) {
            // == x-pipe (waves 0-3): own 16 rows, fully wave-local ==
            // A. poll own <=5 chunks (lanes 0..4 spin, relaxed + one fence)
            const long Ob = (long)s*SLAB + (long)(a0 + wv*16)*40 - SPLIT;
            if (Ob + 640 > 0) {
                long o0 = Ob < 0 ? 0 : Ob;
                int i0 = (int)(o0 >> 7);
                int i1 = (int)((Ob + 639) >> 7);
                if (l <= i1 - i0) {
                    int i = i0 + l;
                    int t = i >> 9, p = i & 511;
                    while (__hip_atomic_load(&flags[p], __ATOMIC_RELAXED,
                                             __HIP_MEMORY_SCOPE_AGENT) < t + 1)
                        __builtin_amdgcn_s_sleep(1);
                }
                __builtin_amdgcn_fence(__ATOMIC_ACQUIRE, "agent");
            }
            // B. direct global->reg loads of this lane's fragment floats
            //    row = wv*16+cl, f in [kb*8, kb*8+8); kb==0 also f 32..39
            int row = wv*16 + cl;
            long V4 = (long)s*(SLAB/4) + (long)(a0 + row)*10 + kb*2;
            float4 v0 = (V4 < SPLIT4) ? ((const float4*)traj)[V4]
                                      : ((const float4*)out)[V4 - SPLIT4];
            float4 v1 = (V4+1 < SPLIT4) ? ((const float4*)traj)[V4+1]
                                        : ((const float4*)out)[V4+1 - SPLIT4];
            float4 v2{0.f,0.f,0.f,0.f}, v3{0.f,0.f,0.f,0.f};
            if (kb == 0) {
                long V8 = V4 + 8;
                v2 = (V8 < SPLIT4) ? ((const float4*)traj)[V8]
                                   : ((const float4*)out)[V8 - SPLIT4];
                v3 = (V8+1 < SPLIT4) ? ((const float4*)traj)[V8+1]
                                     : ((const float4*)out)[V8+1 - SPLIT4];
            }
            // C. h-part MFMAs in the load-latency shadow
#pragma unroll
            for (int mt = 0; mt < 2; ++mt) {
                const short* hb = &Xs[(gang*32 + mt*16 + cl)*XSTRIDE + kb*8];
                bf16x8 hf0 = *(const bf16x8*)(hb);
                bf16x8 hf1 = *(const bf16x8*)(hb + 32);
#pragma unroll
                for (int g = 0; g < 4; ++g) {
                    acc[mt][g] = __builtin_amdgcn_mfma_f32_16x16x32_bf16(hf0, bw[g][0], acc[mt][g], 0, 0, 0);
                    acc[mt][g] = __builtin_amdgcn_mfma_f32_16x16x32_bf16(hf1, bw[g][1], acc[mt][g], 0, 0, 0);
                }
            }
            // D. LN1 stats from f32 regs; reduce over kb (lanes ^16, ^32)
            float s1 = v0.x+v0.y+v0.z+v0.w + v1.x+v1.y+v1.z+v1.w
                     + v2.x+v2.y+v2.z+v2.w + v3.x+v3.y+v3.z+v3.w;
            float s2 = v0.x*v0.x+v0.y*v0.y+v0.z*v0.z+v0.w*v0.w
                     + v1.x*v1.x+v1.y*v1.y+v1.z*v1.z+v1.w*v1.w
                     + v2.x*v2.x+v2.y*v2.y+v2.z*v2.z+v2.w*v2.w
                     + v3.x*v3.x+v3.y*v3.y+v3.z*v3.z+v3.w*v3.w;
            s1 += __shfl_xor(s1, 16, 64); s2 += __shfl_xor(s2, 16, 64);
            s1 += __shfl_xor(s1, 32, 64); s2 += __shfl_xor(s2, 32, 64);
            if (kb == 0) {    // lane l==cl holds row-cl stats
                float m = s1 * (1.f/IN_F);
                St[(wv*16 + cl)*2]     = m;
                St[(wv*16 + cl)*2 + 1] = rsqrtf(s2*(1.f/IN_F) - m*m + LN_EPS);
            }
            // E. pack A-frags + embedding MFMA (K pad handled by ew zeros)
            bf16x8 a0f{f2bf(v0.x),f2bf(v0.y),f2bf(v0.z),f2bf(v0.w),
                       f2bf(v1.x),f2bf(v1.y),f2bf(v1.z),f2bf(v1.w)};
            bf16x8 a1f{f2bf(v2.x),f2bf(v2.y),f2bf(v2.z),f2bf(v2.w),
                       f2bf(v3.x),f2bf(v3.y),f2bf(v3.z),f2bf(v3.w)};
            f32x4 dacc = f32x4{0.f, 0.f, 0.f, 0.f};
            dacc = __builtin_amdgcn_mfma_f32_16x16x32_bf16(a0f, ew[0], dacc, 0, 0, 0);
            dacc = __builtin_amdgcn_mfma_f32_16x16x32_bf16(a1f, ew[1], dacc, 0, 0, 0);
            // F. epilogue (same-wave St; compiler inserts lgkm waits) -> Xs.x
#pragma unroll
            for (int r = 0; r < 4; ++r) {
                int rw = wv*16 + kb*4 + r;
                float2 st = *(const float2*)&St[rw*2];
                float xv = st.y*(dacc[r] - st.x*cst[C_SGW+cl]) + cst[C_BW+cl];
                Xs[rw*XSTRIDE + 64 + cl] = f2bf(lrelu(xv));
            }
        } else {
            // == waves 4-7: h-part MFMAs while x-pipe polls/loads ==
#pragma unroll
            for (int mt = 0; mt < 2; ++mt) {
                const short* hb = &Xs[(gang*32 + mt*16 + cl)*XSTRIDE + kb*8];
                bf16x8 hf0 = *(const bf16x8*)(hb);
                bf16x8 hf1 = *(const bf16x8*)(hb + 32);
#pragma unroll
                for (int g = 0; g < 4; ++g) {
                    acc[mt][g] = __builtin_amdgcn_mfma_f32_16x16x32_bf16(hf0, bw[g][0], acc[mt][g], 0, 0, 0);
                    acc[mt][g] = __builtin_amdgcn_mfma_f32_16x16x32_bf16(hf1, bw[g][1], acc[mt][g], 0, 0, 0);
                }
            }
        }
        __syncthreads();   // bar1: Xs.x visible; all h-reads retired

        // ---- x-part MFMA (1 K-slice) + LSTM elementwise; h -> Xs.h ----
#pragma unroll
        for (int mt = 0; mt < 2; ++mt) {
            bf16x8 xf = *(const bf16x8*)&Xs[(gang*32 + mt*16 + cl)*XSTRIDE + 64 + kb*8];
#pragma unroll
            for (int g = 0; g < 4; ++g)
                acc[mt][g] = __builtin_amdgcn_mfma_f32_16x16x32_bf16(xf, bw[g][2], acc[mt][g], 0, 0, 0);
        }
#pragma unroll
        for (int mt = 0; mt < 2; ++mt) {
            int abase = gang*32 + mt*16 + kb*4;
#pragma unroll
            for (int r = 0; r < 4; ++r) {
                float cn = fsigmoid(acc[mt][1][r]) * cs[mt][r]
                         + fsigmoid(acc[mt][0][r]) * ftanh(acc[mt][2][r]);
                float hn = fsigmoid(acc[mt][3][r]) * ftanh(cn);
                cs[mt][r] = cn;
                Xs[(abase + r)*XSTRIDE + nh] = f2bf(hn);
            }
        }
        __syncthreads();   // bar2: new h visible

        // ---- LN2 (8 thr/agent) + folded h2p -> out (write-through) ----
        {
            int a = tid >> 3, p = tid & 7;
            bf16x8 hv = *(const bf16x8*)&Xs[a*XSTRIDE + p*8];
            float s1 = 0.f, s2 = 0.f, d0 = 0.f, d1 = 0.f;
#pragma unroll
            for (int j = 0; j < 8; ++j) {
                float f = bf2f(hv[j]);
                float2 gw = *(const float2*)&cst[C_G2 + (p*8 + j)*2];
                s1 += f; s2 += f*f;
                d0 += f*gw.x; d1 += f*gw.y;
            }
#pragma unroll
            for (int mk = 1; mk < 8; mk <<= 1) {
                s1 += __shfl_xor(s1, mk, 64);
                s2 += __shfl_xor(s2, mk, 64);
                d0 += __shfl_xor(d0, mk, 64);
                d1 += __shfl_xor(d1, mk, 64);
            }
            if (p < 2) {
                float m   = s1 * (1.f/64);
                float inv = rsqrtf(s2*(1.f/64) - m*m + LN_EPS);
                float dd  = (p == 0) ? d0 : d1;
                float val = inv*(dd - m*cst[C_SG2+p]) + cst[C_B2+p];
                __hip_atomic_store(&out[s*SLAB + (a0 + a)*2 + p], val,
                                   __ATOMIC_RELAXED, __HIP_MEMORY_SCOPE_AGENT);
            }
        }

        // ---- publish: relaxed flag store after full drain ----
        if (s != PRED-1) {
            __syncthreads();   // bar3: out stores drained (vmcnt 0)
            if (tid == 0)
                __hip_atomic_store(&flags[bid], s+1, __ATOMIC_RELAXED,
                                   __HIP_MEMORY_SCOPE_AGENT);
        }
    }
}

extern "C" void kernel_launch(void* const* d_in, const int* in_sizes, int n_in,
                              void* d_out, int out_size, void* d_ws, size_t ws_size,
                              hipStream_t stream) {
    const float* traj  = (const float*)d_in[0];
    // d_in[1] = traj_rel (unused)
    const float* dec_h = (const float*)d_in[2];
    const float* W_ih  = (const float*)d_in[3];
    const float* W_hh  = (const float*)d_in[4];
    const float* b_ih  = (const float*)d_in[5];
    const float* b_hh  = (const float*)d_in[6];
    const float* emb_W = (const float*)d_in[7];
    const float* emb_b = (const float*)d_in[8];
    const float* h2p_W = (const float*)d_in[9];
    const float* h2p_b = (const float*)d_in[10];
    const float* ln1_g = (const float*)d_in[11];
    const float* ln1_b = (const float*)d_in[12];
    const float* ln2_g = (const float*)d_in[13];
    const float* ln2_b = (const float*)d_in[14];
    float* out = (float*)d_out;
    int*   flg = (int*)d_ws;

    persist_kernel<<<NBLK, BTH, 0, stream>>>(
        traj, out, dec_h, W_ih, W_hh, b_ih, b_hh, emb_W, emb_b,
        h2p_W, h2p_b, ln1_g, ln1_b, ln2_g, ln2_b, flg);
}

// Round 4
// 448.701 us; speedup vs baseline: 1.0770x; 1.0770x over previous
//
#include <hip/hip_runtime.h>
#include <hip/hip_bf16.h>

#define NAGENTS 32768
#define SLAB    65536            // NAGENTS*2 floats per time-step
#define SPLIT   1310720          // 20*SLAB
#define SPLIT4  327680           // SPLIT/4
#define PRED    30
#define IN_F    40
#define LN_EPS  1e-5f
#define APB     128              // agents per block
#define NBLK    (NAGENTS/APB)    // 256 = 1 block/CU -> co-resident by construction
#define BTH     1024
#define XSTRIDE 104              // shorts/agent row in Xs: h 0..63, x 64..79, 0 80..95, pad
#define RSTR    72               // shorts/agent row in Rs: 40 data + 24 zero + 8 pad
#define LOG2E   1.44269504088896f

typedef short bf16x8 __attribute__((ext_vector_type(8)));
typedef float f32x4  __attribute__((ext_vector_type(4)));

#define C_SGW  0      // 16  : sum_f ln1g[f]*embW[e,f]
#define C_BW   16     // 16  : sum_f ln1b[f]*embW[e,f] + emb_b[e]
#define C_G2   32     // 128 : g2WT[k*2+d] = ln2g[k]*h2pW[d,k]
#define C_SG2  160    // 2
#define C_B2   162    // 2
#define C_BIAS 164    // 256 : (b_ih + b_hh) * gate-scale (log2e-folded)
#define C_TOT  420

__device__ __forceinline__ float frcp(float x){ return __builtin_amdgcn_rcpf(x); }
__device__ __forceinline__ float fexp2(float x){ return __builtin_amdgcn_exp2f(x); }
__device__ __forceinline__ float lrelu(float x){ return x > 0.f ? x : 0.01f*x; }
__device__ __forceinline__ short f2bf(float x){
    unsigned u = __float_as_uint(x);
    return (short)((u + 0x7FFFu + ((u>>16)&1u)) >> 16);   // RNE (precompute only)
}
__device__ __forceinline__ float bf2f(short s){
    return __uint_as_float(((unsigned)(unsigned short)s) << 16);
}
__device__ __forceinline__ unsigned pk_bf16(float a, float b){
    __hip_bfloat162 h = __float22bfloat162_rn(float2{a, b});   // v_cvt_pk_bf16_f32
    return *reinterpret_cast<unsigned*>(&h);
}

__global__ __launch_bounds__(BTH, 4)
void persist_kernel(const float* __restrict__ traj,
                    float* __restrict__ out,
                    const float* __restrict__ dec_h,
                    const float* __restrict__ W_ih, const float* __restrict__ W_hh,
                    const float* __restrict__ b_ih, const float* __restrict__ b_hh,
                    const float* __restrict__ emb_W, const float* __restrict__ emb_b,
                    const float* __restrict__ h2p_W, const float* __restrict__ h2p_b,
                    const float* __restrict__ ln1_g, const float* __restrict__ ln1_b,
                    const float* __restrict__ ln2_g, const float* __restrict__ ln2_b,
                    int* __restrict__ flags)   // ws: flags[b] = # steps agent-block b done
{
    __shared__ short Rs[APB*RSTR];      // bf16 window rows, k-pad zeroed
    __shared__ short Xs[APB*XSTRIDE];   // gates A operand: h 0..63, x 64..79, 0 80..95
    __shared__ float cst[C_TOT];

    const int tid  = threadIdx.x;
    // XCD-clustering swizzle: consecutive agent-blocks share an XCD (bijective).
    const int bid  = ((blockIdx.x & 7) << 5) | (blockIdx.x >> 3);
    const int a0   = bid * APB;
    const int l    = tid & 63;
    const int wv   = tid >> 6;            // 0..15
    const int gang = wv >> 2;             // 0..3 : 32 agents each (gates GEMM)
    const int wvin = wv & 3;
    const int cl   = l & 15;
    const int kb   = l >> 4;
    const int nh   = wvin*16 + cl;        // gate-elem column this lane owns

    // ---- one-time folded-constant precompute (per block) ----
    if (tid < 16) {
        int e = tid;
        float s = 0.f, b = 0.f;
        for (int f = 0; f < IN_F; ++f) {
            float wf = emb_W[e*40 + f];
            s += ln1_g[f] * wf;
            b += ln1_b[f] * wf;
        }
        cst[C_SGW + e] = s;
        cst[C_BW + e]  = b + emb_b[e];
    }
    if (tid < 128) {
        int k = tid >> 1, d = tid & 1;
        cst[C_G2 + tid] = ln2_g[k] * h2p_W[d*64 + k];
    }
    if (tid < 2) {
        int d = tid;
        float s = 0.f, b = 0.f;
        for (int k = 0; k < 64; ++k) {
            float wf = h2p_W[d*64 + k];
            s += ln2_g[k] * wf;
            b += ln2_b[k] * wf;
        }
        cst[C_SG2 + d] = s;
        cst[C_B2 + d]  = b + h2p_b[d];
    }
    if (tid >= 256 && tid < 512) {        // gate biases, log2e-folded
        int idx = tid - 256;
        float sc = ((idx >> 6) == 2) ? (-2.f*LOG2E) : (-LOG2E);
        cst[C_BIAS + idx] = (b_ih[idx] + b_hh[idx]) * sc;
    }

    // ---- gates-B fragments, log2e-folded: k 0..63 W_hh, 64..79 W_ih, 80..95 0 ----
    bf16x8 bw[4][3];
#pragma unroll
    for (int g = 0; g < 4; ++g) {
        float sc = (g == 2) ? (-2.f*LOG2E) : (-LOG2E);
#pragma unroll
        for (int ks = 0; ks < 3; ++ks) {
            int n = g*64 + nh;
            bf16x8 v;
#pragma unroll
            for (int j = 0; j < 8; ++j) {
                int k = ks*32 + kb*8 + j;
                float f = 0.f;
                if (k < 64)      f = W_hh[n*64 + k];
                else if (k < 80) f = W_ih[n*16 + (k-64)];
                v[j] = f2bf(f * sc);
            }
            bw[g][ks] = v;
        }
    }

    // ---- embedding-B fragments: B[k=f][n=e] = ln1g[f]*embW[e,f], k>=40 -> 0 ----
    bf16x8 ew[2];
#pragma unroll
    for (int ks = 0; ks < 2; ++ks) {
        bf16x8 v;
#pragma unroll
        for (int j = 0; j < 8; ++j) {
            int k = ks*32 + kb*8 + j;
            float f = (k < IN_F) ? ln1_g[k] * emb_W[cl*40 + k] : 0.f;
            v[j] = f2bf(f);
        }
        ew[ks] = v;
    }

    // ---- init Xs.h from dec_h (k 0..63); zero pads once ----
    for (int i = tid; i < APB*16; i += BTH) {
        int a = i >> 4, q = i & 15;
        float4 hv = ((const float4*)dec_h)[(a0 + a)*16 + q];
        uint2 pv{ pk_bf16(hv.x, hv.y), pk_bf16(hv.z, hv.w) };
        *(uint2*)&Xs[a*XSTRIDE + q*4] = pv;
    }
    if (tid < APB*2) {      // Xs k-pad [80,96)
        int a = tid >> 1, hf = tid & 1;
        *(bf16x8*)&Xs[a*XSTRIDE + 80 + hf*8] = bf16x8{0,0,0,0,0,0,0,0};
    }
    if (tid < APB*3) {      // Rs k-pad [40,64)
        int a = tid / 3, seg = tid - a*3;
        *(bf16x8*)&Rs[a*RSTR + 40 + seg*8] = bf16x8{0,0,0,0,0,0,0,0};
    }

    // ---- c state fp32 in registers for all 30 steps ----
    float cs[2][4];
#pragma unroll
    for (int mt = 0; mt < 2; ++mt)
#pragma unroll
        for (int r = 0; r < 4; ++r) cs[mt][r] = 0.f;

    __syncthreads();

    for (int s = 0; s < PRED; ++s) {
        // ---- P0. wait for producer chunks (proven protocol) ----
        {
            const long Ob = (long)s*SLAB + (long)a0*IN_F - SPLIT;
            const long Oe = Ob + APB*IN_F;
            if (Oe > 0) {
                long o0 = Ob < 0 ? 0 : Ob;
                int i0 = (int)(o0 >> 8);
                int i1 = (int)((Oe - 1) >> 8);
                for (int i = i0 + tid; i <= i1; i += BTH) {
                    int t = i >> 8, p = i & 255;
                    while (__hip_atomic_load(&flags[p], __ATOMIC_ACQUIRE,
                                             __HIP_MEMORY_SCOPE_AGENT) < t + 1)
                        __builtin_amdgcn_s_sleep(1);
                }
            }
        }
        __syncthreads();   // bar A

        // ---- P1. issue coalesced staging loads (regs) ----
        const int Gb4 = s*(SLAB/4) + bid*(APB*IN_F/4);
        const int G0 = Gb4 + tid;
        float4 v0 = (G0 < SPLIT4) ? ((const float4*)traj)[G0]
                                  : ((const float4*)out)[G0 - SPLIT4];
        float4 v1;
        const bool extra = (tid < (APB*IN_F/4 - BTH));    // 256 threads carry 2
        if (extra) {
            int G1 = G0 + BTH;
            v1 = (G1 < SPLIT4) ? ((const float4*)traj)[G1]
                               : ((const float4*)out)[G1 - SPLIT4];
        }

        // ---- P2. acc = folded bias; h-part gates GEMM in load shadow ----
        f32x4 acc[2][4];
#pragma unroll
        for (int g = 0; g < 4; ++g) {
            float bb = cst[C_BIAS + g*64 + nh];
            acc[0][g] = f32x4{bb, bb, bb, bb};
            acc[1][g] = f32x4{bb, bb, bb, bb};
        }
#pragma unroll
        for (int mt = 0; mt < 2; ++mt) {
            const short* hb = &Xs[(gang*32 + mt*16 + cl)*XSTRIDE + kb*8];
            bf16x8 hf0 = *(const bf16x8*)(hb);
            bf16x8 hf1 = *(const bf16x8*)(hb + 32);
#pragma unroll
            for (int g = 0; g < 4; ++g) {
                acc[mt][g] = __builtin_amdgcn_mfma_f32_16x16x32_bf16(hf0, bw[g][0], acc[mt][g], 0, 0, 0);
                acc[mt][g] = __builtin_amdgcn_mfma_f32_16x16x32_bf16(hf1, bw[g][1], acc[mt][g], 0, 0, 0);
            }
        }

        // ---- P3. pack staged regs -> Rs ----
        {
            int a = tid / 10, f4 = tid - a*10;
            uint2 w{ pk_bf16(v0.x, v0.y), pk_bf16(v0.z, v0.w) };
            *(uint2*)&Rs[a*RSTR + f4*4] = w;
            if (extra) {
                int i2 = tid + BTH, a2 = i2 / 10, f42 = i2 - a2*10;
                uint2 w2{ pk_bf16(v1.x, v1.y), pk_bf16(v1.z, v1.w) };
                *(uint2*)&Rs[a2*RSTR + f42*4] = w2;
            }
        }
        __syncthreads();   // bar B: Rs ready; all h-reads retired

        // ---- P4. waves 0-7: embed MFMA + fused LN1 stats + epilogue -> Xs.x ----
        if (wv < 8) {
            const short* base = &Rs[(wv*16 + cl)*RSTR + kb*8];
            bf16x8 a0f = *(const bf16x8*)(base);        // k kb*8..+8
            bf16x8 a1f = *(const bf16x8*)(base + 32);   // k 32+kb*8..+8
            f32x4 dacc = f32x4{0.f, 0.f, 0.f, 0.f};
            dacc = __builtin_amdgcn_mfma_f32_16x16x32_bf16(a0f, ew[0], dacc, 0, 0, 0);
            dacc = __builtin_amdgcn_mfma_f32_16x16x32_bf16(a1f, ew[1], dacc, 0, 0, 0);
            // LN1 stats from this lane's 16 k-values (pad zeros contribute 0)
            float s1 = 0.f, s2 = 0.f;
#pragma unroll
            for (int j = 0; j < 8; ++j) {
                float f0 = bf2f(a0f[j]), f1 = bf2f(a1f[j]);
                s1 += f0 + f1; s2 += f0*f0 + f1*f1;
            }
            s1 += __shfl_xor(s1, 16, 64); s2 += __shfl_xor(s2, 16, 64);
            s1 += __shfl_xor(s1, 32, 64); s2 += __shfl_xor(s2, 32, 64);
            float m  = s1 * (1.f/IN_F);                 // stats for agent wv*16+cl
            float iv = rsqrtf(s2*(1.f/IN_F) - m*m + LN_EPS);
            float sgw = cst[C_SGW + cl], bwc = cst[C_BW + cl];
            float xr[4];
#pragma unroll
            for (int r = 0; r < 4; ++r) {               // D rows = kb*4+r: fetch their stats
                float mm = __shfl(m,  kb*4 + r, 64);
                float ii = __shfl(iv, kb*4 + r, 64);
                xr[r] = lrelu(ii*(dacc[r] - mm*sgw) + bwc);
            }
            unsigned u01 = pk_bf16(xr[0], xr[1]);
            unsigned u23 = pk_bf16(xr[2], xr[3]);
            int rb = (wv*16 + kb*4)*XSTRIDE + 64 + cl;
            Xs[rb]             = (short)(u01 & 0xFFFFu);
            Xs[rb + XSTRIDE]   = (short)(u01 >> 16);
            Xs[rb + 2*XSTRIDE] = (short)(u23 & 0xFFFFu);
            Xs[rb + 3*XSTRIDE] = (short)(u23 >> 16);
        }
        __syncthreads();   // bar D: Xs.x ready

        // ---- P6. x-part MFMA + LSTM elementwise (log2e-folded); h -> Xs.h ----
#pragma unroll
        for (int mt = 0; mt < 2; ++mt) {
            bf16x8 xf = *(const bf16x8*)&Xs[(gang*32 + mt*16 + cl)*XSTRIDE + 64 + kb*8];
#pragma unroll
            for (int g = 0; g < 4; ++g)
                acc[mt][g] = __builtin_amdgcn_mfma_f32_16x16x32_bf16(xf, bw[g][2], acc[mt][g], 0, 0, 0);
        }
#pragma unroll
        for (int mt = 0; mt < 2; ++mt) {
            int abase = gang*32 + mt*16 + kb*4;
            float hn[4];
#pragma unroll
            for (int r = 0; r < 4; ++r) {
                // acc already = {-log2e*i, -log2e*f, -2log2e*g, -log2e*o}
                float ei = fexp2(acc[mt][0][r]);        // e^-i
                float ef = fexp2(acc[mt][1][r]);        // e^-f
                float eg = fexp2(acc[mt][2][r]);        // e^-2g
                float eo = fexp2(acc[mt][3][r]);        // e^-o
                float r1   = frcp((1.f+ei)*(1.f+eg));
                float tgsi = (1.f-eg)*r1;               // sigma(i)*tanh(g)
                float sf   = frcp(1.f+ef);              // sigma(f)
                float cn   = fmaf(cs[mt][r], sf, tgsi);
                float t2   = fexp2(cn * (-2.f*LOG2E));  // e^-2c
                float r2   = frcp((1.f+eo)*(1.f+t2));
                hn[r]      = (1.f-t2)*r2;               // sigma(o)*tanh(c)
                cs[mt][r]  = cn;
            }
            unsigned u01 = pk_bf16(hn[0], hn[1]);
            unsigned u23 = pk_bf16(hn[2], hn[3]);
            int hb = abase*XSTRIDE + nh;
            Xs[hb]             = (short)(u01 & 0xFFFFu);
            Xs[hb + XSTRIDE]   = (short)(u01 >> 16);
            Xs[hb + 2*XSTRIDE] = (short)(u23 & 0xFFFFu);
            Xs[hb + 3*XSTRIDE] = (short)(u23 >> 16);
        }
        __syncthreads();   // bar E: new h visible

        // ---- P7. LN2 (8 thr/agent) + folded h2p -> out (write-through) ----
        {
            int a = tid >> 3, p = tid & 7;
            bf16x8 hv = *(const bf16x8*)&Xs[a*XSTRIDE + p*8];
            float s1 = 0.f, s2 = 0.f, d0 = 0.f, d1 = 0.f;
#pragma unroll
            for (int j = 0; j < 8; ++j) {
                float f = bf2f(hv[j]);
                float2 gw = *(const float2*)&cst[C_G2 + (p*8 + j)*2];
                s1 += f; s2 += f*f;
                d0 += f*gw.x; d1 += f*gw.y;
            }
#pragma unroll
            for (int mk = 1; mk < 8; mk <<= 1) {
                s1 += __shfl_xor(s1, mk, 64);
                s2 += __shfl_xor(s2, mk, 64);
                d0 += __shfl_xor(d0, mk, 64);
                d1 += __shfl_xor(d1, mk, 64);
            }
            if (p < 2) {
                float m   = s1 * (1.f/64);
                float inv = rsqrtf(s2*(1.f/64) - m*m + LN_EPS);
                float dd  = (p == 0) ? d0 : d1;
                float val = inv*(dd - m*cst[C_SG2+p]) + cst[C_B2+p];
                __hip_atomic_store(&out[s*SLAB + (a0 + a)*2 + p], val,
                                   __ATOMIC_RELAXED, __HIP_MEMORY_SCOPE_AGENT);
            }
        }

        // ---- publish: relaxed flag store after full drain ----
        if (s != PRED-1) {
            __syncthreads();   // bar F: out stores drained (vmcnt 0)
            if (tid == 0)
                __hip_atomic_store(&flags[bid], s+1, __ATOMIC_RELAXED,
                                   __HIP_MEMORY_SCOPE_AGENT);
        }
    }
}

extern "C" void kernel_launch(void* const* d_in, const int* in_sizes, int n_in,
                              void* d_out, int out_size, void* d_ws, size_t ws_size,
                              hipStream_t stream) {
    const float* traj  = (const float*)d_in[0];
    // d_in[1] = traj_rel (unused)
    const float* dec_h = (const float*)d_in[2];
    const float* W_ih  = (const float*)d_in[3];
    const float* W_hh  = (const float*)d_in[4];
    const float* b_ih  = (const float*)d_in[5];
    const float* b_hh  = (const float*)d_in[6];
    const float* emb_W = (const float*)d_in[7];
    const float* emb_b = (const float*)d_in[8];
    const float* h2p_W = (const float*)d_in[9];
    const float* h2p_b = (const float*)d_in[10];
    const float* ln1_g = (const float*)d_in[11];
    const float* ln1_b = (const float*)d_in[12];
    const float* ln2_g = (const float*)d_in[13];
    const float* ln2_b = (const float*)d_in[14];
    float* out = (float*)d_out;
    int*   flg = (int*)d_ws;

    persist_kernel<<<NBLK, BTH, 0, stream>>>(
        traj, out, dec_h, W_ih, W_hh, b_ih, b_hh, emb_W, emb_b,
        h2p_W, h2p_b, ln1_g, ln1_b, ln2_g, ln2_b, flg);
}

// Round 6
// 374.583 us; speedup vs baseline: 1.2901x; 1.1979x over previous
//
#include <hip/hip_runtime.h>
#include <hip/hip_bf16.h>

#define NAGENTS 32768
#define SLAB    65536            // NAGENTS*2
#define SPLIT   1310720          // 20*SLAB
#define SPLIT4  327680           // SPLIT/4
#define PRED    30
#define IN_F    40
#define LN_EPS  1e-5f
#define APB     128              // agents per block
#define NBLK    (NAGENTS/APB)    // 256 = 1 block/CU -> co-resident by construction
#define BTH     1024
#define XSTRIDE 104              // shorts per agent row in Xs (96 used + 8 pad)
#define RSTR    72               // shorts per agent row in Rs (40 data + 24 zero + 8 pad)
#define LOG2E   1.44269504088896f

typedef short bf16x8 __attribute__((ext_vector_type(8)));
typedef short bf16x4 __attribute__((ext_vector_type(4)));
typedef float f32x4  __attribute__((ext_vector_type(4)));

// cst float offsets — EXACT r11 layout (bias/sgW/bW in LDS, NOT registers:
// hoisting to regs pushed the 128-reg/wave budget into scratch spills.)
#define C_SGW  0      // 16  : sum_f ln1g[f]*embW[e,f]
#define C_BW   16     // 16  : sum_f ln1b[f]*embW[e,f] + emb_b[e]
#define C_G2   32     // 128 : g2WT[k*2+d] = ln2g[k]*h2pW[d,k]
#define C_SG2  160    // 2
#define C_B2   162    // 2
#define C_BIAS 164    // 256 : (b_ih + b_hh) * gate-scale (log2e-folded)
#define C_TOT  420

__device__ __forceinline__ float frcp(float x){ return __builtin_amdgcn_rcpf(x); }
__device__ __forceinline__ float fexp2(float x){ return __builtin_amdgcn_exp2f(x); }
__device__ __forceinline__ float lrelu(float x){ return x > 0.f ? x : 0.01f*x; }
__device__ __forceinline__ short f2bf(float x){
    unsigned u = __float_as_uint(x);
    return (short)((u + 0x7FFFu + ((u>>16)&1u)) >> 16);   // RNE
}
__device__ __forceinline__ float bf2f(short s){
    return __uint_as_float(((unsigned)(unsigned short)s) << 16);
}
__device__ __forceinline__ unsigned pk_bf16(float a, float b){
    __hip_bfloat162 h = __float22bfloat162_rn(float2{a, b});
    return *reinterpret_cast<unsigned*>(&h);
}

__global__ __launch_bounds__(BTH, 4)
void persist_kernel(const float* __restrict__ traj,
                    float* __restrict__ out,
                    const float* __restrict__ dec_h,
                    const float* __restrict__ W_ih, const float* __restrict__ W_hh,
                    const float* __restrict__ b_ih, const float* __restrict__ b_hh,
                    const float* __restrict__ emb_W, const float* __restrict__ emb_b,
                    const float* __restrict__ h2p_W, const float* __restrict__ h2p_b,
                    const float* __restrict__ ln1_g, const float* __restrict__ ln1_b,
                    const float* __restrict__ ln2_g, const float* __restrict__ ln2_b,
                    int* __restrict__ flags)   // ws: flags[b] = # steps block b completed
{
    __shared__ short Rs[APB*RSTR];      // bf16 window rows, A-layout, k-pad zeroed
    __shared__ short Xs[APB*XSTRIDE];   // bf16 A-operand [agent][k]: 0..16 x, 16..80 h, 80..96 zero
    __shared__ float Ds[APB*16];        // embedding dot outputs
    __shared__ float St[APB*2];         // LN1 stats: m, inv per agent
    __shared__ float cst[C_TOT];

    const int tid  = threadIdx.x;
    const int bid  = blockIdx.x;
    const int a0   = bid * APB;
    const int l    = tid & 63;
    const int wv   = tid >> 6;            // 0..15
    const int gang = wv >> 2;             // 0..3 : 32 agents each (gates GEMM)
    const int wvin = wv & 3;
    const int cl   = l & 15;
    const int kb   = l >> 4;
    const int nh   = wvin*16 + cl;        // gate-elem column this lane owns

    // ---- one-time folded-constant precompute (per block) ----
    if (tid < 16) {
        int e = tid;
        float s = 0.f, b = 0.f;
        for (int f = 0; f < IN_F; ++f) {
            float wf = emb_W[e*40 + f];
            s += ln1_g[f] * wf;
            b += ln1_b[f] * wf;
        }
        cst[C_SGW + e] = s;
        cst[C_BW + e]  = b + emb_b[e];
    }
    if (tid < 128) {
        int k = tid >> 1, d = tid & 1;
        cst[C_G2 + tid] = ln2_g[k] * h2p_W[d*64 + k];
    }
    if (tid < 2) {
        int d = tid;
        float s = 0.f, b = 0.f;
        for (int k = 0; k < 64; ++k) {
            float wf = h2p_W[d*64 + k];
            s += ln2_g[k] * wf;
            b += ln2_b[k] * wf;
        }
        cst[C_SG2 + d] = s;
        cst[C_B2 + d]  = b + h2p_b[d];
    }
    if (tid >= 256 && tid < 512) {        // gate biases, log2e-folded
        int idx = tid - 256;
        float sc = ((idx >> 6) == 2) ? (-2.f*LOG2E) : (-LOG2E);
        cst[C_BIAS + idx] = (b_ih[idx] + b_hh[idx]) * sc;
    }

    // ---- gates-B fragments (weights, log2e-folded), once for all 30 steps ----
    bf16x8 bw[4][3];
#pragma unroll
    for (int g = 0; g < 4; ++g) {
        float sc = (g == 2) ? (-2.f*LOG2E) : (-LOG2E);
#pragma unroll
        for (int ks = 0; ks < 3; ++ks) {
            int n = g*64 + nh;
            bf16x8 v;
#pragma unroll
            for (int j = 0; j < 8; ++j) {
                int k = ks*32 + kb*8 + j;
                float f = 0.f;
                if (k < 16)      f = W_ih[n*16 + k];
                else if (k < 80) f = W_hh[n*64 + (k-16)];
                v[j] = f2bf(f * sc);
            }
            bw[g][ks] = v;
        }
    }

    // ---- embedding-B fragments: B[k=f][n=e] = ln1g[f]*embW[e,f], K-pad 0 ----
    bf16x8 ew[2];
#pragma unroll
    for (int ks = 0; ks < 2; ++ks) {
        bf16x8 v;
#pragma unroll
        for (int j = 0; j < 8; ++j) {
            int k = ks*32 + kb*8 + j;
            float f = (k < IN_F) ? ln1_g[k] * emb_W[cl*40 + k] : 0.f;
            v[j] = f2bf(f);
        }
        ew[ks] = v;
    }

    // ---- init h region of Xs from dec_h; zero pads (written once) ----
    for (int i = tid; i < APB*16; i += BTH) {
        int a = i >> 4, q = i & 15;
        float4 hv = ((const float4*)dec_h)[(a0 + a)*16 + q];
        uint2 pv{ pk_bf16(hv.x, hv.y), pk_bf16(hv.z, hv.w) };
        *(uint2*)&Xs[a*XSTRIDE + 16 + q*4] = pv;
    }
    if (tid < APB*2) {      // Xs k-pad [80,96)
        int a = tid >> 1, hf = tid & 1;
        *(bf16x8*)&Xs[a*XSTRIDE + 80 + hf*8] = bf16x8{0,0,0,0,0,0,0,0};
    }
    for (int i = tid; i < APB*3; i += BTH) {   // Rs k-pad [40,64)
        int a = i / 3, seg = i - a*3;
        *(bf16x8*)&Rs[a*RSTR + 40 + seg*8] = bf16x8{0,0,0,0,0,0,0,0};
    }

    // ---- c state fp32 in registers for all 30 steps ----
    float cs[2][4];
#pragma unroll
    for (int mt = 0; mt < 2; ++mt)
#pragma unroll
        for (int r = 0; r < 4; ++r) cs[mt][r] = 0.f;

    __syncthreads();

    for (int s = 0; s < PRED; ++s) {
        // ---- 0. wait for producer chunks (r11-exact poll phase) ----
        {
            const long Ob = (long)s*SLAB + (long)a0*IN_F - SPLIT;
            const long Oe = Ob + APB*IN_F;    // exclusive
            if (Oe > 0) {
                long o0 = Ob < 0 ? 0 : Ob;
                int i0 = (int)(o0 >> 8);
                int i1 = (int)((Oe - 1) >> 8);
                for (int i = i0 + tid; i <= i1; i += BTH) {
                    int t = i >> 8, p = i & 255;
                    while (__hip_atomic_load(&flags[p], __ATOMIC_ACQUIRE,
                                             __HIP_MEMORY_SCOPE_AGENT) < t + 1)
                        __builtin_amdgcn_s_sleep(1);
                }
            }
        }
        __syncthreads();

        // ---- 1. stage rows -> packed bf16 Rs. traj: plain cached float4.
        //         out: agent-scope coherent 8B atomic loads (sc1) — a plain
        //         load can hit a stale per-XCD L2 line surviving from the
        //         previous launch (re-poison runs => wrong data, flaky fail).
        {
            const int Gb4 = s*(SLAB/4) + bid*(APB*IN_F/4);
            for (int i = tid; i < APB*IN_F/4; i += BTH) {    // 1280 float4
                int a = i / 10, f4 = i - a*10;
                int G4 = Gb4 + i;
                float4 v;
                if (G4 < SPLIT4) {
                    v = ((const float4*)traj)[G4];
                } else {
                    const unsigned long long* p8 =
                        (const unsigned long long*)out + (size_t)(G4 - SPLIT4)*2;
                    unsigned long long u0 = __hip_atomic_load(p8,     __ATOMIC_RELAXED,
                                                              __HIP_MEMORY_SCOPE_AGENT);
                    unsigned long long u1 = __hip_atomic_load(p8 + 1, __ATOMIC_RELAXED,
                                                              __HIP_MEMORY_SCOPE_AGENT);
                    v.x = __uint_as_float((unsigned)(u0 & 0xFFFFFFFFu));
                    v.y = __uint_as_float((unsigned)(u0 >> 32));
                    v.z = __uint_as_float((unsigned)(u1 & 0xFFFFFFFFu));
                    v.w = __uint_as_float((unsigned)(u1 >> 32));
                }
                uint2 pv{ pk_bf16(v.x, v.y), pk_bf16(v.z, v.w) };
                *(uint2*)&Rs[a*RSTR + f4*4] = pv;
            }
        }
        __syncthreads();

        // ---- 2a. embedding GEMM (waves 0-7) -> Ds ----
        if (wv < 8) {
            f32x4 dacc = f32x4{0.f, 0.f, 0.f, 0.f};
            const short* base = &Rs[(wv*16 + cl)*RSTR + kb*8];
            bf16x8 a0f = *(const bf16x8*)(base);        // k 0..31
            bf16x8 a1f = *(const bf16x8*)(base + 32);   // k 32..63
            dacc = __builtin_amdgcn_mfma_f32_16x16x32_bf16(a0f, ew[0], dacc, 0, 0, 0);
            dacc = __builtin_amdgcn_mfma_f32_16x16x32_bf16(a1f, ew[1], dacc, 0, 0, 0);
#pragma unroll
            for (int r = 0; r < 4; ++r)
                Ds[(wv*16 + kb*4 + r)*16 + cl] = dacc[r];
        } else {
        // ---- 2b. LN1 stats (waves 8-15): 4 thr/agent over bf16 rows ----
            int t2 = tid - 512;
            int a = t2 >> 2, p = t2 & 3;
            const bf16x8* rp = (const bf16x8*)&Rs[a*RSTR + p*16];
            bf16x8 v0 = rp[0], v1 = rp[1];    // k-pad zeros don't affect sums
            float s1 = 0.f, s2 = 0.f;
#pragma unroll
            for (int j = 0; j < 8; ++j) {
                float f0 = bf2f(v0[j]), f1 = bf2f(v1[j]);
                s1 += f0 + f1; s2 += f0*f0 + f1*f1;
            }
            s1 += __shfl_xor(s1, 1, 64); s2 += __shfl_xor(s2, 1, 64);
            s1 += __shfl_xor(s1, 2, 64); s2 += __shfl_xor(s2, 2, 64);
            if (p == 0) {
                float m = s1 * (1.f/IN_F);
                St[a*2]   = m;
                St[a*2+1] = rsqrtf(s2*(1.f/IN_F) - m*m + LN_EPS);
            }
        }
        __syncthreads();

        // ---- 3. embedding epilogue (all threads, from Ds/St/cst) -> Xs x ----
        {
            int a = tid >> 3, p = tid & 7, e0 = p*2;
            float m = St[a*2], inv = St[a*2+1];
            float D0 = Ds[a*16 + e0], D1 = Ds[a*16 + e0 + 1];
            float x0 = inv*(D0 - m*cst[C_SGW+e0  ]) + cst[C_BW+e0  ];
            float x1 = inv*(D1 - m*cst[C_SGW+e0+1]) + cst[C_BW+e0+1];
            unsigned pv = pk_bf16(lrelu(x0), lrelu(x1));
            *(unsigned*)&Xs[a*XSTRIDE + e0] = pv;
        }
        __syncthreads();

        // ---- 4. gates GEMM via MFMA: gang handles 32 agents, 2 M-tiles ----
        f32x4 acc[2][4];
#pragma unroll
        for (int g = 0; g < 4; ++g) {
            float bb = cst[C_BIAS + g*64 + nh];
            acc[0][g] = f32x4{bb, bb, bb, bb};
            acc[1][g] = f32x4{bb, bb, bb, bb};
        }
#pragma unroll
        for (int mt = 0; mt < 2; ++mt) {
            const short* base = &Xs[(gang*32 + mt*16 + cl)*XSTRIDE + kb*8];
            bf16x8 af0 = *(const bf16x8*)(base);
            bf16x8 af1 = *(const bf16x8*)(base + 32);
            bf16x8 af2 = *(const bf16x8*)(base + 64);
#pragma unroll
            for (int g = 0; g < 4; ++g) {
                acc[mt][g] = __builtin_amdgcn_mfma_f32_16x16x32_bf16(af0, bw[g][0], acc[mt][g], 0, 0, 0);
                acc[mt][g] = __builtin_amdgcn_mfma_f32_16x16x32_bf16(af1, bw[g][1], acc[mt][g], 0, 0, 0);
                acc[mt][g] = __builtin_amdgcn_mfma_f32_16x16x32_bf16(af2, bw[g][2], acc[mt][g], 0, 0, 0);
            }
        }
        __syncthreads();   // all Xs reads done before h overwrite

        // ---- 5. LSTM elementwise, log2e-folded (validated in rd4): h -> Xs ----
        //      acc = {-log2e*i, -log2e*f, -2log2e*g, -log2e*o} pre-activations
#pragma unroll
        for (int mt = 0; mt < 2; ++mt) {
            int abase = gang*32 + mt*16 + kb*4;
#pragma unroll
            for (int r = 0; r < 4; ++r) {
                float ei = fexp2(acc[mt][0][r]);        // e^-i
                float ef = fexp2(acc[mt][1][r]);        // e^-f
                float eg = fexp2(acc[mt][2][r]);        // e^-2g
                float eo = fexp2(acc[mt][3][r]);        // e^-o
                float r1   = frcp((1.f+ei)*(1.f+eg));
                float tgsi = (1.f-eg)*r1;               // sigma(i)*tanh(g)
                float sf   = frcp(1.f+ef);              // sigma(f)
                float cn   = fmaf(cs[mt][r], sf, tgsi);
                float t2   = fexp2(cn * (-2.f*LOG2E));  // e^-2c
                float r2   = frcp((1.f+eo)*(1.f+t2));
                float hn   = (1.f-t2)*r2;               // sigma(o)*tanh(c)
                cs[mt][r]  = cn;
                Xs[(abase + r)*XSTRIDE + 16 + nh] = f2bf(hn);
            }
        }
        __syncthreads();

        // ---- 6. LN2 (split 8-way) + folded h2p -> out (write-through) ----
        {
            int a = tid >> 3, p = tid & 7;
            bf16x8 hv = *(const bf16x8*)&Xs[a*XSTRIDE + 16 + p*8];
            float s1 = 0.f, s2 = 0.f, d0 = 0.f, d1 = 0.f;
#pragma unroll
            for (int j = 0; j < 8; ++j) {
                float f = bf2f(hv[j]);
                float2 gw = *(const float2*)&cst[C_G2 + (p*8 + j)*2];
                s1 += f; s2 += f*f;
                d0 += f*gw.x; d1 += f*gw.y;
            }
#pragma unroll
            for (int mk = 1; mk < 8; mk <<= 1) {
                s1 += __shfl_xor(s1, mk, 64);
                s2 += __shfl_xor(s2, mk, 64);
                d0 += __shfl_xor(d0, mk, 64);
                d1 += __shfl_xor(d1, mk, 64);
            }
            if (p < 2) {
                float m   = s1 * (1.f/64);
                float inv = rsqrtf(s2*(1.f/64) - m*m + LN_EPS);
                float dd  = (p == 0) ? d0 : d1;
                float val = inv*(dd - m*cst[C_SG2+p]) + cst[C_B2+p];
                __hip_atomic_store(&out[s*SLAB + (a0 + a)*2 + p], val,
                                   __ATOMIC_RELAXED, __HIP_MEMORY_SCOPE_AGENT);
            }
        }

        // ---- 7. publish progress: RELEASE flag store after vmcnt drain ----
        if (s != PRED-1) {
            __syncthreads();
            if (tid == 0)
                __hip_atomic_store(&flags[bid], s+1, __ATOMIC_RELEASE,
                                   __HIP_MEMORY_SCOPE_AGENT);
        }
    }
}

extern "C" void kernel_launch(void* const* d_in, const int* in_sizes, int n_in,
                              void* d_out, int out_size, void* d_ws, size_t ws_size,
                              hipStream_t stream) {
    const float* traj  = (const float*)d_in[0];
    // d_in[1] = traj_rel (unused)
    const float* dec_h = (const float*)d_in[2];
    const float* W_ih  = (const float*)d_in[3];
    const float* W_hh  = (const float*)d_in[4];
    const float* b_ih  = (const float*)d_in[5];
    const float* b_hh  = (const float*)d_in[6];
    const float* emb_W = (const float*)d_in[7];
    const float* emb_b = (const float*)d_in[8];
    const float* h2p_W = (const float*)d_in[9];
    const float* h2p_b = (const float*)d_in[10];
    const float* ln1_g = (const float*)d_in[11];
    const float* ln1_b = (const float*)d_in[12];
    const float* ln2_g = (const float*)d_in[13];
    const float* ln2_b = (const float*)d_in[14];
    float* out = (float*)d_out;
    int*   flg = (int*)d_ws;

    persist_kernel<<<NBLK, BTH, 0, stream>>>(
        traj, out, dec_h, W_ih, W_hh, b_ih, b_hh, emb_W, emb_b,
        h2p_W, h2p_b, ln1_g, ln1_b, ln2_g, ln2_b, flg);
}